// Round 1
// baseline (461.410 us; speedup 1.0000x reference)
//
#include <hip/hip_runtime.h>

// Subtraction op: x [8,32,96,96] f32, K=7, S=1, P=3, D=1, reflect pad.
// out [n*c, 49, 9216]: out[p][k][s] = x[p][oh][ow] - x_refl[p][oh+i-3][ow+j-3]
// Write-BW bound: 462 MB out vs 9.4 MB in. Floor ~73 us @ 6.3 TB/s.

constexpr int H = 96, W = 96, PP = 3, KS = 7;
constexpr int PLANE = H * W;      // 9216 floats = 36 KB
constexpr int NF4 = PLANE / 4;    // 2304 float4 per plane
constexpr int W4 = W / 4;         // 24 float4 per row

__device__ __forceinline__ int refl(int t) {
    // single reflection valid for t in [-(H-1), 2H-2]; here t in [-3, 98]
    int r = t < 0 ? -t : t;
    return r >= H ? 2 * (H - 1) - r : r;
}

__global__ __launch_bounds__(256) void subtraction_kernel(
    const float* __restrict__ x, float* __restrict__ out) {
    __shared__ float lds[PLANE];

    const int plane = blockIdx.x;   // n*c index
    const int kc    = blockIdx.y;   // i = row offset index, 0..6
    const int di    = kc - PP;      // row delta, uniform across block

    // Stage the whole 96x96 plane into LDS (float4, coalesced).
    const float* xp = x + (size_t)plane * PLANE;
    for (int i = threadIdx.x; i < NF4; i += 256)
        ((float4*)lds)[i] = ((const float4*)xp)[i];
    __syncthreads();

    // Output base for this block: plane*49*9216 + (kc*7)*9216
    float* op = out + (size_t)plane * (KS * KS) * PLANE
                    + (size_t)kc * KS * PLANE;

    #pragma unroll
    for (int kk = 0; kk < KS; ++kk) {      // j = col offset index
        const int dj = kk - PP;
        float4* o4 = (float4*)(op + (size_t)kk * PLANE);
        for (int f = threadIdx.x; f < NF4; f += 256) {
            const int row = f / W4;
            const int c4  = f - row * W4;
            const int ow0 = c4 * 4;
            const int nr  = refl(row + di);
            const float* nrow = lds + nr * W;
            const float4 c = ((const float4*)lds)[f];
            float4 v;
            v.x = c.x - nrow[refl(ow0 + 0 + dj)];
            v.y = c.y - nrow[refl(ow0 + 1 + dj)];
            v.z = c.z - nrow[refl(ow0 + 2 + dj)];
            v.w = c.w - nrow[refl(ow0 + 3 + dj)];
            o4[f] = v;
        }
    }
}

extern "C" void kernel_launch(void* const* d_in, const int* in_sizes, int n_in,
                              void* d_out, int out_size, void* d_ws, size_t ws_size,
                              hipStream_t stream) {
    const float* x = (const float*)d_in[0];
    float* out = (float*)d_out;
    const int n_planes = in_sizes[0] / PLANE;  // 8*32 = 256
    dim3 grid(n_planes, KS);
    subtraction_kernel<<<grid, 256, 0, stream>>>(x, out);
}

// Round 2
// 457.728 us; speedup vs baseline: 1.0080x; 1.0080x over previous
//
#include <hip/hip_runtime.h>

// Subtraction: x [8,32,96,96] f32, K=7, S=1, P=3, D=1, reflect pad.
// out [plane][49][9216]: out[p][i*7+j][oh*96+ow] = x[p][oh][ow] - x_refl[p][oh+i-3][ow+j-3]
// Write-BW bound: 462 MB out vs 9.4 MB in. Floor ~73 us @ 6.3 TB/s.
//
// Strategy: per (plane, i) block. Stage plane into LDS as [96][104] padded rows
// with reflected columns baked into the pads (left pad = 4 floats so the center
// quad is 16B-aligned). Per output quad: 1 aligned b128 center read + 3 aligned
// b128 neighbor-row reads cover ALL 7 dj windows as static register selects
// (kk fully unrolled -> no runtime indexing, no scratch). Conflict-free LDS,
// float4 coalesced stores.

constexpr int H = 96, W = 96, PP = 3, KS = 7;
constexpr int PLANE = H * W;        // 9216 floats
constexpr int W4 = W / 4;           // 24 quads per row
constexpr int NQ = PLANE / 4;       // 2304 quads per plane
constexpr int LROW = 104;           // padded row stride in floats (416 B, 16B-mult)

__device__ __forceinline__ int refl(int t) {
    // valid for t in [-3, 98]
    int r = t < 0 ? -t : t;
    return r >= H ? 2 * (H - 1) - r : r;
}

__global__ __launch_bounds__(256) void subtraction_kernel(
    const float* __restrict__ x, float* __restrict__ out) {
    __shared__ float lds[H * LROW];  // 39.9 KB -> 4 blocks/CU

    const int tid   = threadIdx.x;
    const int plane = blockIdx.x;   // n*c
    const int kc    = blockIdx.y;   // i (row-offset index 0..6)
    const int di    = kc - PP;

    const float* xp = x + (size_t)plane * PLANE;

    // Stage: quad i -> lds[row][4 + col*4] (aligned float4 writes)
    for (int i = tid; i < NQ; i += 256) {
        const int r = i / W4, c = i - r * W4;
        *(float4*)(lds + r * LROW + 4 + c * 4) = ((const float4*)xp)[i];
    }
    // Bake reflected columns into pads (cols -3..-1 -> 3..1; 96..98 -> 94..92)
    if (tid < H) {
        const float* g = xp + tid * W;
        float* pr = lds + tid * LROW;
        pr[0] = 0.f;     pr[1] = g[3];    pr[2] = g[2];    pr[3] = g[1];
        pr[100] = g[94]; pr[101] = g[93]; pr[102] = g[92]; pr[103] = 0.f;
    }
    __syncthreads();

    float* op = out + (size_t)plane * (KS * KS) * PLANE + (size_t)kc * KS * PLANE;

    for (int it = 0; it < 9; ++it) {         // 9*256 = 2304 quads exactly
        const int f   = tid + it * 256;
        const int row = f / W4;
        const int c4  = f - row * W4;
        const int nr  = refl(row + di);
        const float* crow = lds + row * LROW;
        const float* nrow = lds + nr * LROW;
        const float4 c  = *(const float4*)(crow + 4 + c4 * 4);   // center quad
        const float4 q0 = *(const float4*)(nrow + c4 * 4);       // floats ow0-4..ow0-1 (padded)
        const float4 q1 = *(const float4*)(nrow + c4 * 4 + 4);   // floats ow0..ow0+3
        const float4 q2 = *(const float4*)(nrow + c4 * 4 + 8);   // floats ow0+4..ow0+7
        const float r12[12] = {q0.x, q0.y, q0.z, q0.w,
                               q1.x, q1.y, q1.z, q1.w,
                               q2.x, q2.y, q2.z, q2.w};
        #pragma unroll
        for (int kk = 0; kk < KS; ++kk) {
            const int s = kk + 1;            // window start: dj = kk-3 -> offset 4+dj
            float4 v;
            v.x = c.x - r12[s + 0];
            v.y = c.y - r12[s + 1];
            v.z = c.z - r12[s + 2];
            v.w = c.w - r12[s + 3];
            ((float4*)(op + (size_t)kk * PLANE))[f] = v;
        }
    }
}

extern "C" void kernel_launch(void* const* d_in, const int* in_sizes, int n_in,
                              void* d_out, int out_size, void* d_ws, size_t ws_size,
                              hipStream_t stream) {
    const float* x = (const float*)d_in[0];
    float* out = (float*)d_out;
    const int n_planes = in_sizes[0] / PLANE;  // 256
    dim3 grid(n_planes, KS);
    subtraction_kernel<<<grid, 256, 0, stream>>>(x, out);
}